// Round 14
// baseline (670.323 us; speedup 1.0000x reference)
//
#include <hip/hip_runtime.h>
#include <hip/hip_cooperative_groups.h>

namespace cg = cooperative_groups;

// Problem constants (fixed by the reference).
constexpr int N = 100000;   // nodes
constexpr int E = 1600000;  // edges
constexpr int D = 128;      // feature dim (both layers)
constexpr int M = 5000;     // mask size

constexpr int MF_BLKS = (N + 255) / 256;           // 391 mfma-gemm blocks (256 rows each)

// Counting-sort CSR build parameters.
constexpr int NB  = 196;                           // buckets: dst>>9, 512 nodes each
constexpr int EB  = 2048;                          // edges per hist/partition unit
constexpr int NPB = (E + EB - 1) / EB;             // 782 partition units
constexpr int HL  = NB * NPB;                      // 153272 flat histogram entries
constexpr int SC_BLKS = (HL + 1023) / 1024;        // 150 scan units
constexpr int PREP_BLKS = 64;                      // weight-prep units (16384 threads)
constexpr int MB_BLKS = (M + 255) / 256;           // 20 maskbit units

// Cooperative CSR kernel: stage unit counts. Grid must be <= co-resident capacity;
// 768 = 3 blocks/CU at <=170 VGPR, ~8 KB LDS -- ample margin.
constexpr int CSR_GRID = 768;
constexpr int S0_UNITS = 2 + NPB + PREP_BLKS;      // zero-bitmaps + hist + weight prep
constexpr int S1_UNITS = MB_BLKS + SC_BLKS;        // maskbit + scan partials
constexpr int S2_UNITS = NPB + SC_BLKS;            // needed-scan + scan final
constexpr int S3_UNITS = NPB;                      // partition
constexpr int S4_UNITS = NB;                       // local sort

typedef __attribute__((ext_vector_type(8))) short bf16x8;
typedef __attribute__((ext_vector_type(4))) float f32x4;

// ---------------- bf16 helpers (RNE pack, cheap unpack) ----------------

__device__ __forceinline__ unsigned int pack_bf16x2(float a, float b) {
    unsigned int ua = __float_as_uint(a);
    unsigned int ub = __float_as_uint(b);
    ua = (ua + 0x7FFFu + ((ua >> 16) & 1u)) >> 16;
    ub = (ub + 0x7FFFu + ((ub >> 16) & 1u)) & 0xFFFF0000u;
    return ua | ub;
}
__device__ __forceinline__ unsigned short bf16_rne(float a) {
    unsigned int ua = __float_as_uint(a);
    return (unsigned short)((ua + 0x7FFFu + ((ua >> 16) & 1u)) >> 16);
}
__device__ __forceinline__ float bf16_lo(unsigned int u) { return __uint_as_float(u << 16); }
__device__ __forceinline__ float bf16_hi(unsigned int u) { return __uint_as_float(u & 0xFFFF0000u); }

// ---------------- cooperative CSR build: 5 stages, 4 grid syncs ----------------
// All stages resource-light (~8 KB LDS, low VGPR) so 768 blocks co-reside.
// record: bits[8:0]=d&511, bits[28:9]=src, bits[63:32]=ew bits

__global__ __launch_bounds__(256) void k_csr(const int* __restrict__ src,
                                             const int* __restrict__ dst,
                                             const float* __restrict__ ew,
                                             const int* __restrict__ mask,
                                             const float* __restrict__ W1,
                                             const float* __restrict__ W2,
                                             int* __restrict__ hist,
                                             int* __restrict__ bs,
                                             int* __restrict__ histS,
                                             unsigned long long* __restrict__ tmp,
                                             int2* __restrict__ pairs,
                                             float* __restrict__ dis,
                                             int* __restrict__ rowStart,
                                             unsigned int* __restrict__ maskbit,
                                             unsigned int* __restrict__ needed,
                                             unsigned int* __restrict__ Wt1,
                                             unsigned int* __restrict__ Wt2) {
    cg::grid_group grid = cg::this_grid();
    const int t = threadIdx.x;
    const int nb = gridDim.x;

    __shared__ int   h[NB];       // hist counts / partition cursors
    __shared__ int   sh[256];     // scanf block-sums scan
    __shared__ int   waveS[4];
    __shared__ int   cnt[512];
    __shared__ float wsum[512];
    __shared__ int   off[512];

    // ---- S0: zero bitmaps + per-unit bucket histogram + weight prep ----
    for (int u = blockIdx.x; u < S0_UNITS; u += nb) {
        if (u < 2) {
            unsigned int* p = (u == 0) ? maskbit : needed;
            for (int i = t; i < 4096; i += 256) p[i] = 0u;
        } else if (u < 2 + NPB) {
            const int ub = u - 2;
            if (t < NB) h[t] = 0;
            __syncthreads();
            const int base = ub * EB;
#pragma unroll
            for (int i = 0; i < 8; ++i) {
                int e = base + t + i * 256;
                if (e < E) {
                    int b = __builtin_nontemporal_load(dst + e) >> 9;
                    atomicAdd(&h[b], 1);
                }
            }
            __syncthreads();
            if (t < NB) hist[t * NPB + ub] = h[t];
            __syncthreads();
        } else {
            int gi = (u - 2 - NPB) * 256 + t;   // 16384 total
            const float* W = (gi < 8192) ? W1 : W2;
            unsigned int* Wt = (gi < 8192) ? Wt1 : Wt2;
            int idx = gi & 8191;
            int n = idx >> 6, kk = idx & 63;
            float a = W[(2 * kk) * D + n];
            float b = W[(2 * kk + 1) * D + n];
            Wt[idx] = pack_bf16x2(a, b);
        }
    }
    grid.sync();

    // ---- S1: maskbit marking + histogram scan partials ----
    for (int u = blockIdx.x; u < S1_UNITS; u += nb) {
        if (u < MB_BLKS) {
            int i = u * 256 + t;
            if (i < M) {
                int n = mask[i];
                atomicOr(&maskbit[n >> 5], 1u << (n & 31));
                atomicOr(&needed[n >> 5], 1u << (n & 31));
            }
        } else {
            const int ub = u - MB_BLKS;
            const int idx = ub * 1024 + t * 4;
            int s = 0;
            if (idx + 3 < HL) {
                int4 c = *(const int4*)(hist + idx);
                s = c.x + c.y + c.z + c.w;
            } else {
                for (int i = 0; i < 4; ++i) if (idx + i < HL) s += hist[idx + i];
            }
            for (int o = 32; o > 0; o >>= 1) s += __shfl_down(s, o);
            if ((t & 63) == 0) waveS[t >> 6] = s;
            __syncthreads();
            if (t == 0) bs[ub] = waveS[0] + waveS[1] + waveS[2] + waveS[3];
            __syncthreads();
        }
    }
    grid.sync();

    // ---- S2: needed-set edge scan + final histogram scan ----
    for (int u = blockIdx.x; u < S2_UNITS; u += nb) {
        if (u < NPB) {
            const int base = u * EB;
#pragma unroll
            for (int i = 0; i < 8; ++i) {
                int e = base + t + i * 256;
                if (e < E) {
                    int d = __builtin_nontemporal_load(dst + e);
                    if ((maskbit[d >> 5] >> (d & 31)) & 1u) {
                        int s = src[e];
                        atomicOr(&needed[s >> 5], 1u << (s & 31));
                    }
                }
            }
        } else {
            const int ub = u - NPB;
            sh[t] = (t < SC_BLKS) ? bs[t] : 0;
            __syncthreads();
            for (int o = 1; o < 256; o <<= 1) {
                int v2 = (t >= o) ? sh[t - o] : 0;
                __syncthreads();
                sh[t] += v2;
                __syncthreads();
            }
            const int bOff = sh[ub] - bs[ub];

            const int idx = ub * 1024 + t * 4;
            int4 c = make_int4(0, 0, 0, 0);
            if (idx + 3 < HL) c = *(const int4*)(hist + idx);
            else {
                if (idx + 0 < HL) c.x = hist[idx + 0];
                if (idx + 1 < HL) c.y = hist[idx + 1];
                if (idx + 2 < HL) c.z = hist[idx + 2];
                if (idx + 3 < HL) c.w = hist[idx + 3];
            }
            int s = c.x + c.y + c.z + c.w;
            const int lane = t & 63, wv = t >> 6;
            int v = s;
            for (int o = 1; o < 64; o <<= 1) {
                int u2 = __shfl_up(v, o);
                if (lane >= o) v += u2;
            }
            if (lane == 63) waveS[wv] = v;
            __syncthreads();
            int wb = 0;
            for (int w = 0; w < 4; ++w) if (w < wv) wb += waveS[w];
            int excl = bOff + wb + (v - s);

            int4 rs;
            rs.x = excl;
            rs.y = excl + c.x;
            rs.z = excl + c.x + c.y;
            rs.w = excl + c.x + c.y + c.z;
            if (idx + 3 < HL) *(int4*)(histS + idx) = rs;
            else {
                if (idx + 0 < HL) histS[idx + 0] = rs.x;
                if (idx + 1 < HL) histS[idx + 1] = rs.y;
                if (idx + 2 < HL) histS[idx + 2] = rs.z;
                if (idx + 3 < HL) histS[idx + 3] = rs.w;
            }
            __syncthreads();
        }
    }
    grid.sync();

    // ---- S3: partition edges into bucket-contiguous tmp (LDS cursors in h) ----
    for (int u = blockIdx.x; u < S3_UNITS; u += nb) {
        if (t < NB) h[t] = histS[t * NPB + u];
        __syncthreads();
        const int eb = u * EB;
#pragma unroll
        for (int i = 0; i < 8; ++i) {
            int e = eb + t + i * 256;
            if (e < E) {
                int d = __builtin_nontemporal_load(dst + e);
                int s = __builtin_nontemporal_load(src + e);
                float w = __builtin_nontemporal_load(ew + e);
                int b = d >> 9;
                int pos = atomicAdd(&h[b], 1);
                unsigned long long rec =
                    ((unsigned long long)(unsigned int)__float_as_int(w) << 32) |
                    ((unsigned int)s << 9) | (unsigned int)(d & 511);
                __builtin_nontemporal_store(rec, tmp + pos);
            }
        }
        __syncthreads();
    }
    grid.sync();

    // ---- S4: per-bucket local sort; writes rowStart, dis, node-sorted pairs ----
    for (int u = blockIdx.x; u < S4_UNITS; u += nb) {
        const int segBeg = histS[u * NPB];
        const int segEnd = (u + 1 < NB) ? histS[(u + 1) * NPB] : E;

        cnt[t] = 0; cnt[t + 256] = 0;
        wsum[t] = 0.f; wsum[t + 256] = 0.f;
        __syncthreads();

        for (int e = segBeg + t; e < segEnd; e += 256) {
            unsigned long long rec = tmp[e];
            int dl = (int)(rec & 511);
            float w = __uint_as_float((unsigned int)(rec >> 32));
            atomicAdd(&cnt[dl], 1);
            atomicAdd(&wsum[dl], w);
        }
        __syncthreads();

        const int i0 = t * 2, i1 = t * 2 + 1;
        const int c0 = cnt[i0], c1 = cnt[i1];
        const int pv = c0 + c1;
        const int lane = t & 63, wv = t >> 6;
        int v = pv;
        for (int o = 1; o < 64; o <<= 1) {
            int u2 = __shfl_up(v, o);
            if (lane >= o) v += u2;
        }
        if (lane == 63) waveS[wv] = v;
        __syncthreads();
        int wb = 0;
        for (int w = 0; w < 4; ++w) if (w < wv) wb += waveS[w];
        const int ex = wb + v - pv;
        off[i0] = ex;
        off[i1] = ex + c0;
        const int node0 = u * 512 + i0, node1 = u * 512 + i1;
        if (node0 < N) { rowStart[node0] = segBeg + ex;      dis[node0] = rsqrtf(1.0f + wsum[i0]); }
        if (node1 < N) { rowStart[node1] = segBeg + ex + c0; dis[node1] = rsqrtf(1.0f + wsum[i1]); }
        cnt[i0] = 0; cnt[i1] = 0;
        if (u == NB - 1 && t == 0) rowStart[N] = E;
        __syncthreads();

        for (int e = segBeg + t; e < segEnd; e += 256) {
            unsigned long long rec = tmp[e];
            int dl = (int)(rec & 511);
            int s  = (int)((rec >> 9) & 0xFFFFF);
            unsigned int wbits = (unsigned int)(rec >> 32);
            int r = atomicAdd(&cnt[dl], 1);
            pairs[segBeg + off[dl] + r] = make_int2(s, (int)wbits);
        }
        __syncthreads();
    }
}

// ---------------- MFMA GEMM body: 256 rows/block, 4 waves; wave = 64 rows x 128 cols ----------------
// A-frag: A[m=lane&15][k=quad*8+j]; B-frag: B[k=quad*8+j][n=lane&15];
// D: col=lane&15, row=quad*4+reg  (HW-verified layouts, 16x16x32 bf16).
// W^T staged in LDS with 68-uint row stride (bank-conflict padding).

template <bool BF16IN>
__device__ __forceinline__ void gemm_mfma_body(const void* __restrict__ Xin,
                                               const unsigned int* __restrict__ Wt,
                                               unsigned short* __restrict__ out, int blk) {
    __shared__ unsigned int Ws[128 * 68];
    const int t = threadIdx.x;
#pragma unroll
    for (int i = 0; i < 8; ++i) {
        int f4 = t + i * 256;        // uint4 index, 2048 total
        int n = f4 >> 4;
        int k4 = f4 & 15;
        uint4 w = ((const uint4*)Wt)[f4];
        *(uint4*)(&Ws[n * 68 + k4 * 4]) = w;
    }
    __syncthreads();

    const int wv = t >> 6, lane = t & 63;
    const int q = lane >> 4, l15 = lane & 15;
    const int rowBase = blk * 256 + wv * 64;

    f32x4 acc[4][8] = {};
#pragma unroll
    for (int kc = 0; kc < 4; ++kc) {
        bf16x8 af[4];
#pragma unroll
        for (int rt = 0; rt < 4; ++rt) {
            int row = rowBase + rt * 16 + l15;
            if (row > N - 1) row = N - 1;   // tail: duplicate last row, stores guarded
            union { uint4 u; bf16x8 v; } cv;
            if (BF16IN) {
                cv.u = *(const uint4*)((const unsigned int*)Xin + (size_t)row * 64 + kc * 16 + q * 4);
            } else {
                const float* xr = (const float*)Xin + (size_t)row * D + kc * 32 + q * 8;
                float4 x0 = *(const float4*)xr;
                float4 x1 = *(const float4*)(xr + 4);
                cv.u.x = pack_bf16x2(x0.x, x0.y);
                cv.u.y = pack_bf16x2(x0.z, x0.w);
                cv.u.z = pack_bf16x2(x1.x, x1.y);
                cv.u.w = pack_bf16x2(x1.z, x1.w);
            }
            af[rt] = cv.v;
        }
#pragma unroll
        for (int ct = 0; ct < 8; ++ct) {
            union { uint4 u; bf16x8 v; } bv;
            bv.u = *(const uint4*)(&Ws[(ct * 16 + l15) * 68 + kc * 16 + q * 4]);
#pragma unroll
            for (int rt = 0; rt < 4; ++rt)
                acc[rt][ct] = __builtin_amdgcn_mfma_f32_16x16x32_bf16(af[rt], bv.v, acc[rt][ct], 0, 0, 0);
        }
    }

#pragma unroll
    for (int rt = 0; rt < 4; ++rt) {
#pragma unroll
        for (int ct = 0; ct < 8; ++ct) {
            int col = ct * 16 + l15;
#pragma unroll
            for (int r = 0; r < 4; ++r) {
                int row = rowBase + rt * 16 + q * 4 + r;
                if (row < N) out[(size_t)row * D + col] = bf16_rne(acc[rt][ct][r]);
            }
        }
    }
}

__global__ __launch_bounds__(256) void k_gemm1(const float* __restrict__ x,
                                               const unsigned int* __restrict__ Wt1,
                                               unsigned short* __restrict__ A) {
    gemm_mfma_body<false>(x, Wt1, A, blockIdx.x);
}

__global__ __launch_bounds__(256) void k_gemm2(const unsigned short* __restrict__ B,
                                               const unsigned int* __restrict__ Wt2,
                                               unsigned short* __restrict__ A2) {
    gemm_mfma_body<true>(B, Wt2, A2, blockIdx.x);
}

// ---------------- aggregate layer 1 (needed nodes only): B = relu(dis*sum + A/deg + b1) ----------------
// One wave per node; lane owns a col-pair. v = ew*dis[src] computed on the fly
// (pairs/dis loads are wave-uniform -> broadcast). 8 gathers in flight.

__global__ __launch_bounds__(256) void k_aggregate(const unsigned int* __restrict__ Hb,
                                                   const int2* __restrict__ pairs,
                                                   const int* __restrict__ rowStart,
                                                   const float* __restrict__ dis,
                                                   const unsigned int* __restrict__ needed,
                                                   const float* __restrict__ b,
                                                   unsigned int* __restrict__ outB) {
    int node = blockIdx.x * 4 + (threadIdx.x >> 6);
    if (node >= N) return;
    if (!((needed[node >> 5] >> (node & 31)) & 1u)) return;  // row never consumed downstream
    int lane = threadIdx.x & 63;
    int beg = rowStart[node], end = rowStart[node + 1];

    float ax = 0.f, ay = 0.f;
    int j = beg;
    for (; j + 7 < end; j += 8) {
        int2 p[8];
        float vv[8];
        unsigned int h[8];
#pragma unroll
        for (int i = 0; i < 8; ++i) p[i] = pairs[j + i];
#pragma unroll
        for (int i = 0; i < 8; ++i) { h[i] = Hb[(size_t)p[i].x * 64 + lane]; vv[i] = dis[p[i].x]; }
#pragma unroll
        for (int i = 0; i < 8; ++i) {
            float v = __int_as_float(p[i].y) * vv[i];
            ax += bf16_lo(h[i]) * v;
            ay += bf16_hi(h[i]) * v;
        }
    }
    for (; j + 3 < end; j += 4) {
        int2 p[4];
        float vv[4];
        unsigned int h[4];
#pragma unroll
        for (int i = 0; i < 4; ++i) p[i] = pairs[j + i];
#pragma unroll
        for (int i = 0; i < 4; ++i) { h[i] = Hb[(size_t)p[i].x * 64 + lane]; vv[i] = dis[p[i].x]; }
#pragma unroll
        for (int i = 0; i < 4; ++i) {
            float v = __int_as_float(p[i].y) * vv[i];
            ax += bf16_lo(h[i]) * v;
            ay += bf16_hi(h[i]) * v;
        }
    }
    for (; j < end; ++j) {
        int2 p0 = pairs[j];
        unsigned int h0 = Hb[(size_t)p0.x * 64 + lane];
        float v0 = __int_as_float(p0.y) * dis[p0.x];
        ax += bf16_lo(h0) * v0;
        ay += bf16_hi(h0) * v0;
    }

    float dd = dis[node];
    float sn = dd * dd;  // self-loop norm = 1/deg
    unsigned int hs = Hb[(size_t)node * 64 + lane];
    float2 bb = ((const float2*)b)[lane];
    float ox = fmaxf(ax * dd + bf16_lo(hs) * sn + bb.x, 0.f);
    float oy = fmaxf(ay * dd + bf16_hi(hs) * sn + bb.y, 0.f);
    __builtin_nontemporal_store(pack_bf16x2(ox, oy), outB + (size_t)node * 64 + lane);
}

// ---------------- layer-2 aggregate at mask nodes only -> d_out ----------------

__global__ __launch_bounds__(256) void k_aggregate_mask(const unsigned int* __restrict__ Hb,
                                                        const int2* __restrict__ pairs,
                                                        const int* __restrict__ rowStart,
                                                        const float* __restrict__ dis,
                                                        const float* __restrict__ b,
                                                        const int* __restrict__ mask,
                                                        const int* __restrict__ y,
                                                        float* __restrict__ out) {
    int i = blockIdx.x * 4 + (threadIdx.x >> 6);
    if (i >= M) return;
    int lane = threadIdx.x & 63;
    int node = mask[i];
    int beg = rowStart[node], end = rowStart[node + 1];

    float ax = 0.f, ay = 0.f;
    int j = beg;
    for (; j + 7 < end; j += 8) {
        int2 p[8];
        float vv[8];
        unsigned int h[8];
#pragma unroll
        for (int ii = 0; ii < 8; ++ii) p[ii] = pairs[j + ii];
#pragma unroll
        for (int ii = 0; ii < 8; ++ii) { h[ii] = Hb[(size_t)p[ii].x * 64 + lane]; vv[ii] = dis[p[ii].x]; }
#pragma unroll
        for (int ii = 0; ii < 8; ++ii) {
            float v = __int_as_float(p[ii].y) * vv[ii];
            ax += bf16_lo(h[ii]) * v;
            ay += bf16_hi(h[ii]) * v;
        }
    }
    for (; j < end; ++j) {
        int2 p0 = pairs[j];
        unsigned int h0 = Hb[(size_t)p0.x * 64 + lane];
        float v0 = __int_as_float(p0.y) * dis[p0.x];
        ax += bf16_lo(h0) * v0;
        ay += bf16_hi(h0) * v0;
    }

    float dd = dis[node];
    float sn = dd * dd;
    unsigned int hs = Hb[(size_t)node * 64 + lane];
    float2 bb = ((const float2*)b)[lane];
    float ox = ax * dd + bf16_lo(hs) * sn + bb.x;
    float oy = ay * dd + bf16_hi(hs) * sn + bb.y;
    ((float2*)(out + (size_t)i * D))[lane] = make_float2(ox, oy);
    if (lane == 0) out[(size_t)M * D + i] = (float)y[node];
}

extern "C" void kernel_launch(void* const* d_in, const int* in_sizes, int n_in,
                              void* d_out, int out_size, void* d_ws, size_t ws_size,
                              hipStream_t stream) {
    const float* x  = (const float*)d_in[0];
    const float* ew = (const float*)d_in[1];
    const float* W1 = (const float*)d_in[2];
    const float* b1 = (const float*)d_in[3];
    const float* W2 = (const float*)d_in[4];
    const float* b2 = (const float*)d_in[5];
    const int* eidx = (const int*)d_in[6];
    const int* mask = (const int*)d_in[7];
    const int* y    = (const int*)d_in[8];
    const int* src = eidx;       // edge_index[0]
    const int* dst = eidx + E;   // edge_index[1]

    // Workspace layout (bytes):
    //   dis       @ 0       : N f32       (0.4 MB)
    //   rowStart  @ 512 KB  : N+1 i32     (0.4 MB)
    //   scanBS    @ 1024 KB : SC_BLKS i32
    //   maskbit   @ 1056 KB : 16 KB bitmap (zeroed in k_csr S0)
    //   needed    @ 1072 KB : 16 KB bitmap (zeroed in k_csr S0)
    //   Wt1       @ 1088 KB : 8192 u32    (32 KB)
    //   Wt2       @ 1120 KB : 8192 u32    (32 KB)
    //   hist      @ 1280 KB : HL i32      (613 KB)
    //   histS     @ 1920 KB : HL i32      (613 KB)
    //   pairs     @ 3 MB    : E int2      (12.8 MB)
    //   tmp       @ 16 MB   : E u64       (12.8 MB)
    //   A  (bf16) @ 29 MB   : N*D bf16    (25.6 MB)
    //   B  (bf16) @ 55 MB   : N*D bf16    (25.6 MB)
    //   A2 (bf16) @ 81 MB   : N*D bf16    (25.6 MB)   total ~106.6 MB
    char* ws = (char*)d_ws;
    float* dis      = (float*)(ws);
    int*   rowStart = (int*)(ws + (size_t)512 * 1024);
    int*   scanBS   = (int*)(ws + (size_t)1024 * 1024);
    unsigned int* maskbit = (unsigned int*)(ws + (size_t)1056 * 1024);
    unsigned int* needed  = (unsigned int*)(ws + (size_t)1072 * 1024);
    unsigned int* Wt1 = (unsigned int*)(ws + (size_t)1088 * 1024);
    unsigned int* Wt2 = (unsigned int*)(ws + (size_t)1120 * 1024);
    int*   hist     = (int*)(ws + (size_t)1280 * 1024);
    int*   histS    = (int*)(ws + (size_t)1920 * 1024);
    int2*  pairs    = (int2*)(ws + (size_t)3 * 1024 * 1024);
    unsigned long long* tmp = (unsigned long long*)(ws + (size_t)16 * 1024 * 1024);
    unsigned short* A  = (unsigned short*)(ws + (size_t)29 * 1024 * 1024);
    unsigned short* B  = (unsigned short*)(ws + (size_t)55 * 1024 * 1024);
    unsigned short* A2 = (unsigned short*)(ws + (size_t)81 * 1024 * 1024);

    // --- cooperative CSR build: hist/prep/maskbit -> scans -> partition -> local ---
    void* csrArgs[] = {
        (void*)&src, (void*)&dst, (void*)&ew, (void*)&mask, (void*)&W1, (void*)&W2,
        (void*)&hist, (void*)&scanBS, (void*)&histS, (void*)&tmp, (void*)&pairs,
        (void*)&dis, (void*)&rowStart, (void*)&maskbit, (void*)&needed,
        (void*)&Wt1, (void*)&Wt2,
    };
    (void)hipLaunchCooperativeKernel((const void*)k_csr, dim3(CSR_GRID), dim3(256),
                                     csrArgs, 0, stream);

    // --- layer 1: A = x@W1 (MFMA) ; B = relu(agg(A) + b1) at needed nodes only ---
    hipLaunchKernelGGL(k_gemm1, dim3(MF_BLKS), dim3(256), 0, stream, x, Wt1, A);
    hipLaunchKernelGGL(k_aggregate, dim3((N + 3) / 4), dim3(256), 0, stream,
                       (const unsigned int*)A, pairs, rowStart, dis, needed, b1,
                       (unsigned int*)B);

    // --- layer 2: A2 = B@W2 (MFMA) ; out = agg(A2) at mask nodes ---
    hipLaunchKernelGGL(k_gemm2, dim3(MF_BLKS), dim3(256), 0, stream, B, Wt2, A2);
    hipLaunchKernelGGL(k_aggregate_mask, dim3((M + 3) / 4), dim3(256), 0, stream,
                       (const unsigned int*)A2, pairs, rowStart, dis, b2, mask, y, (float*)d_out);
}

// Round 15
// 296.434 us; speedup vs baseline: 2.2613x; 2.2613x over previous
//
#include <hip/hip_runtime.h>

// Problem constants (fixed by the reference).
constexpr int N = 100000;   // nodes
constexpr int E = 1600000;  // edges
constexpr int D = 128;      // feature dim (both layers)
constexpr int M = 5000;     // mask size

constexpr int MF_BLKS = (N + 255) / 256;           // 391 mfma-gemm blocks (256 rows each)

// Bucketed CSR build (fixed-capacity, atomic reservation -- no global scans).
constexpr int NB  = 196;                           // buckets: dst>>9, 512 nodes each
constexpr int CAP = 10240;                         // slots/bucket (mean 8192, +22 sigma)
constexpr int EB  = 2048;                          // edges per partition block
constexpr int NPB = (E + EB - 1) / EB;             // 782 partition blocks
constexpr int PREP_BLKS = 64;                      // weight-prep blocks
constexpr int MB_BLKS = (M + 255) / 256;           // 20 maskbit blocks

typedef __attribute__((ext_vector_type(8))) short bf16x8;
typedef __attribute__((ext_vector_type(4))) float f32x4;

// ---------------- bf16 helpers (RNE pack, cheap unpack) ----------------

__device__ __forceinline__ unsigned int pack_bf16x2(float a, float b) {
    unsigned int ua = __float_as_uint(a);
    unsigned int ub = __float_as_uint(b);
    ua = (ua + 0x7FFFu + ((ua >> 16) & 1u)) >> 16;
    ub = (ub + 0x7FFFu + ((ub >> 16) & 1u)) & 0xFFFF0000u;
    return ua | ub;
}
__device__ __forceinline__ unsigned short bf16_rne(float a) {
    unsigned int ua = __float_as_uint(a);
    return (unsigned short)((ua + 0x7FFFu + ((ua >> 16) & 1u)) >> 16);
}
__device__ __forceinline__ float bf16_lo(unsigned int u) { return __uint_as_float(u << 16); }
__device__ __forceinline__ float bf16_hi(unsigned int u) { return __uint_as_float(u & 0xFFFF0000u); }

// ---------------- misc1: weight prep + maskbit marking ----------------

__global__ __launch_bounds__(256) void k_misc1(const float* __restrict__ W1,
                                               unsigned int* __restrict__ Wt1,
                                               const float* __restrict__ W2,
                                               unsigned int* __restrict__ Wt2,
                                               const int* __restrict__ mask,
                                               unsigned int* __restrict__ maskbit,
                                               unsigned int* __restrict__ needed) {
    const int t = threadIdx.x;
    if (blockIdx.x < PREP_BLKS) {
        int gi = blockIdx.x * 256 + t;   // 16384 total
        const float* W = (gi < 8192) ? W1 : W2;
        unsigned int* Wt = (gi < 8192) ? Wt1 : Wt2;
        int idx = gi & 8191;
        int n = idx >> 6, kk = idx & 63;
        float a = W[(2 * kk) * D + n];
        float b = W[(2 * kk + 1) * D + n];
        Wt[idx] = pack_bf16x2(a, b);
    } else {
        int i = (blockIdx.x - PREP_BLKS) * 256 + t;
        if (i < M) {
            int n = mask[i];
            atomicOr(&maskbit[n >> 5], 1u << (n & 31));
            atomicOr(&needed[n >> 5], 1u << (n & 31));  // masked nodes need their own row
        }
    }
}

// ---------------- partition: count -> reserve (atomic per bucket) -> scatter ----------------
// Also folds the needed-set edge scan into the first edge read.
// record: bits[8:0]=d&511, bits[28:9]=src, bits[63:32]=ew bits

__global__ __launch_bounds__(256) void k_part(const int* __restrict__ src,
                                              const int* __restrict__ dst,
                                              const float* __restrict__ ew,
                                              const unsigned int* __restrict__ maskbit,
                                              unsigned int* __restrict__ needed,
                                              int* __restrict__ cursors,
                                              unsigned long long* __restrict__ tmp) {
    __shared__ int h[NB];
    __shared__ int base_[NB];
    __shared__ int cur[NB];
    const int t = threadIdx.x;
    if (t < NB) { h[t] = 0; cur[t] = 0; }
    __syncthreads();
    const int eb = blockIdx.x * EB;
#pragma unroll
    for (int i = 0; i < 8; ++i) {
        int e = eb + t + i * 256;
        if (e < E) {
            int d = __builtin_nontemporal_load(dst + e);
            atomicAdd(&h[d >> 9], 1);
            if ((maskbit[d >> 5] >> (d & 31)) & 1u) {   // needed-set marking (fused)
                int s = src[e];
                atomicOr(&needed[s >> 5], 1u << (s & 31));
            }
        }
    }
    __syncthreads();
    if (t < NB && h[t] > 0) base_[t] = atomicAdd(&cursors[t], h[t]);
    __syncthreads();
#pragma unroll
    for (int i = 0; i < 8; ++i) {
        int e = eb + t + i * 256;
        if (e < E) {
            int d = dst[e];                     // L2-hot second read
            int s = src[e];
            float w = ew[e];
            int b = d >> 9;
            int r = atomicAdd(&cur[b], 1);
            int pos = base_[b] + r;
            if (pos < CAP) {                    // defensive; statistically never taken
                unsigned long long rec =
                    ((unsigned long long)(unsigned int)__float_as_int(w) << 32) |
                    ((unsigned int)s << 9) | (unsigned int)(d & 511);
                __builtin_nontemporal_store(rec, tmp + (size_t)b * CAP + pos);
            }
        }
    }
}

// ---------------- local: per-bucket node sort; writes rowBE, dis, node-sorted pairs ----------------

__global__ __launch_bounds__(256) void k_local(const unsigned long long* __restrict__ tmp,
                                               const int* __restrict__ cursors,
                                               float* __restrict__ dis,
                                               int2* __restrict__ rowBE,
                                               int2* __restrict__ pairs) {
    const int b = blockIdx.x;
    const int t = threadIdx.x;
    const int segBeg = b * CAP;
    const int segEnd = segBeg + min(cursors[b], CAP);

    __shared__ int   cnt[512];
    __shared__ float wsum[512];
    __shared__ int   off[512];
    __shared__ int   waveS[4];
    cnt[t] = 0; cnt[t + 256] = 0;
    wsum[t] = 0.f; wsum[t + 256] = 0.f;
    __syncthreads();

    for (int e = segBeg + t; e < segEnd; e += 256) {
        unsigned long long rec = tmp[e];
        int dl = (int)(rec & 511);
        float w = __uint_as_float((unsigned int)(rec >> 32));
        atomicAdd(&cnt[dl], 1);
        atomicAdd(&wsum[dl], w);
    }
    __syncthreads();

    const int i0 = t * 2, i1 = t * 2 + 1;
    const int c0 = cnt[i0], c1 = cnt[i1];
    const int pv = c0 + c1;
    const int lane = t & 63, wv = t >> 6;
    int v = pv;
    for (int o = 1; o < 64; o <<= 1) {
        int u2 = __shfl_up(v, o);
        if (lane >= o) v += u2;
    }
    if (lane == 63) waveS[wv] = v;
    __syncthreads();
    int wb = 0;
    for (int w = 0; w < 4; ++w) if (w < wv) wb += waveS[w];
    const int ex = wb + v - pv;
    off[i0] = ex;
    off[i1] = ex + c0;
    const int node0 = b * 512 + i0, node1 = b * 512 + i1;
    if (node0 < N) {
        rowBE[node0] = make_int2(segBeg + ex, segBeg + ex + c0);
        dis[node0] = rsqrtf(1.0f + wsum[i0]);
    }
    if (node1 < N) {
        rowBE[node1] = make_int2(segBeg + ex + c0, segBeg + ex + c0 + c1);
        dis[node1] = rsqrtf(1.0f + wsum[i1]);
    }
    cnt[i0] = 0; cnt[i1] = 0;
    __syncthreads();

    for (int e = segBeg + t; e < segEnd; e += 256) {
        unsigned long long rec = tmp[e];
        int dl = (int)(rec & 511);
        int s  = (int)((rec >> 9) & 0xFFFFF);
        unsigned int wbits = (unsigned int)(rec >> 32);
        int r = atomicAdd(&cnt[dl], 1);
        pairs[segBeg + off[dl] + r] = make_int2(s, (int)wbits);
    }
}

// ---------------- MFMA GEMM body: 256 rows/block, 4 waves; wave = 64 rows x 128 cols ----------------
// A-frag: A[m=lane&15][k=quad*8+j]; B-frag: B[k=quad*8+j][n=lane&15];
// D: col=lane&15, row=quad*4+reg  (HW-verified layouts, 16x16x32 bf16).
// W^T staged in LDS with 68-uint row stride (bank-conflict padding).

template <bool BF16IN>
__device__ __forceinline__ void gemm_mfma_body(const void* __restrict__ Xin,
                                               const unsigned int* __restrict__ Wt,
                                               unsigned short* __restrict__ out, int blk) {
    __shared__ unsigned int Ws[128 * 68];
    const int t = threadIdx.x;
#pragma unroll
    for (int i = 0; i < 8; ++i) {
        int f4 = t + i * 256;        // uint4 index, 2048 total
        int n = f4 >> 4;
        int k4 = f4 & 15;
        uint4 w = ((const uint4*)Wt)[f4];
        *(uint4*)(&Ws[n * 68 + k4 * 4]) = w;
    }
    __syncthreads();

    const int wv = t >> 6, lane = t & 63;
    const int q = lane >> 4, l15 = lane & 15;
    const int rowBase = blk * 256 + wv * 64;

    f32x4 acc[4][8] = {};
#pragma unroll
    for (int kc = 0; kc < 4; ++kc) {
        bf16x8 af[4];
#pragma unroll
        for (int rt = 0; rt < 4; ++rt) {
            int row = rowBase + rt * 16 + l15;
            if (row > N - 1) row = N - 1;   // tail: duplicate last row, stores guarded
            union { uint4 u; bf16x8 v; } cv;
            if (BF16IN) {
                cv.u = *(const uint4*)((const unsigned int*)Xin + (size_t)row * 64 + kc * 16 + q * 4);
            } else {
                const float* xr = (const float*)Xin + (size_t)row * D + kc * 32 + q * 8;
                float4 x0 = *(const float4*)xr;
                float4 x1 = *(const float4*)(xr + 4);
                cv.u.x = pack_bf16x2(x0.x, x0.y);
                cv.u.y = pack_bf16x2(x0.z, x0.w);
                cv.u.z = pack_bf16x2(x1.x, x1.y);
                cv.u.w = pack_bf16x2(x1.z, x1.w);
            }
            af[rt] = cv.v;
        }
#pragma unroll
        for (int ct = 0; ct < 8; ++ct) {
            union { uint4 u; bf16x8 v; } bv;
            bv.u = *(const uint4*)(&Ws[(ct * 16 + l15) * 68 + kc * 16 + q * 4]);
#pragma unroll
            for (int rt = 0; rt < 4; ++rt)
                acc[rt][ct] = __builtin_amdgcn_mfma_f32_16x16x32_bf16(af[rt], bv.v, acc[rt][ct], 0, 0, 0);
        }
    }

#pragma unroll
    for (int rt = 0; rt < 4; ++rt) {
#pragma unroll
        for (int ct = 0; ct < 8; ++ct) {
            int col = ct * 16 + l15;
#pragma unroll
            for (int r = 0; r < 4; ++r) {
                int row = rowBase + rt * 16 + q * 4 + r;
                if (row < N) out[(size_t)row * D + col] = bf16_rne(acc[rt][ct][r]);
            }
        }
    }
}

__global__ __launch_bounds__(256) void k_gemm1(const float* __restrict__ x,
                                               const unsigned int* __restrict__ Wt1,
                                               unsigned short* __restrict__ A) {
    gemm_mfma_body<false>(x, Wt1, A, blockIdx.x);
}

__global__ __launch_bounds__(256) void k_gemm2(const unsigned short* __restrict__ B,
                                               const unsigned int* __restrict__ Wt2,
                                               unsigned short* __restrict__ A2) {
    gemm_mfma_body<true>(B, Wt2, A2, blockIdx.x);
}

// ---------------- aggregate layer 1 (needed nodes only): B = relu(dis*sum + A/deg + b1) ----------------
// One wave per node; lane owns a col-pair. v = ew*dis[src] computed on the fly
// (pairs/dis loads are wave-uniform -> broadcast). 8 gathers in flight.

__global__ __launch_bounds__(256) void k_aggregate(const unsigned int* __restrict__ Hb,
                                                   const int2* __restrict__ pairs,
                                                   const int2* __restrict__ rowBE,
                                                   const float* __restrict__ dis,
                                                   const unsigned int* __restrict__ needed,
                                                   const float* __restrict__ b,
                                                   unsigned int* __restrict__ outB) {
    int node = blockIdx.x * 4 + (threadIdx.x >> 6);
    if (node >= N) return;
    if (!((needed[node >> 5] >> (node & 31)) & 1u)) return;  // row never consumed downstream
    int lane = threadIdx.x & 63;
    int2 be = rowBE[node];
    int beg = be.x, end = be.y;

    float ax = 0.f, ay = 0.f;
    int j = beg;
    for (; j + 7 < end; j += 8) {
        int2 p[8];
        float vv[8];
        unsigned int h[8];
#pragma unroll
        for (int i = 0; i < 8; ++i) p[i] = pairs[j + i];
#pragma unroll
        for (int i = 0; i < 8; ++i) { h[i] = Hb[(size_t)p[i].x * 64 + lane]; vv[i] = dis[p[i].x]; }
#pragma unroll
        for (int i = 0; i < 8; ++i) {
            float v = __int_as_float(p[i].y) * vv[i];
            ax += bf16_lo(h[i]) * v;
            ay += bf16_hi(h[i]) * v;
        }
    }
    for (; j + 3 < end; j += 4) {
        int2 p[4];
        float vv[4];
        unsigned int h[4];
#pragma unroll
        for (int i = 0; i < 4; ++i) p[i] = pairs[j + i];
#pragma unroll
        for (int i = 0; i < 4; ++i) { h[i] = Hb[(size_t)p[i].x * 64 + lane]; vv[i] = dis[p[i].x]; }
#pragma unroll
        for (int i = 0; i < 4; ++i) {
            float v = __int_as_float(p[i].y) * vv[i];
            ax += bf16_lo(h[i]) * v;
            ay += bf16_hi(h[i]) * v;
        }
    }
    for (; j < end; ++j) {
        int2 p0 = pairs[j];
        unsigned int h0 = Hb[(size_t)p0.x * 64 + lane];
        float v0 = __int_as_float(p0.y) * dis[p0.x];
        ax += bf16_lo(h0) * v0;
        ay += bf16_hi(h0) * v0;
    }

    float dd = dis[node];
    float sn = dd * dd;  // self-loop norm = 1/deg
    unsigned int hs = Hb[(size_t)node * 64 + lane];
    float2 bb = ((const float2*)b)[lane];
    float ox = fmaxf(ax * dd + bf16_lo(hs) * sn + bb.x, 0.f);
    float oy = fmaxf(ay * dd + bf16_hi(hs) * sn + bb.y, 0.f);
    __builtin_nontemporal_store(pack_bf16x2(ox, oy), outB + (size_t)node * 64 + lane);
}

// ---------------- layer-2 aggregate at mask nodes only -> d_out ----------------

__global__ __launch_bounds__(256) void k_aggregate_mask(const unsigned int* __restrict__ Hb,
                                                        const int2* __restrict__ pairs,
                                                        const int2* __restrict__ rowBE,
                                                        const float* __restrict__ dis,
                                                        const float* __restrict__ b,
                                                        const int* __restrict__ mask,
                                                        const int* __restrict__ y,
                                                        float* __restrict__ out) {
    int i = blockIdx.x * 4 + (threadIdx.x >> 6);
    if (i >= M) return;
    int lane = threadIdx.x & 63;
    int node = mask[i];
    int2 be = rowBE[node];
    int beg = be.x, end = be.y;

    float ax = 0.f, ay = 0.f;
    int j = beg;
    for (; j + 7 < end; j += 8) {
        int2 p[8];
        float vv[8];
        unsigned int h[8];
#pragma unroll
        for (int ii = 0; ii < 8; ++ii) p[ii] = pairs[j + ii];
#pragma unroll
        for (int ii = 0; ii < 8; ++ii) { h[ii] = Hb[(size_t)p[ii].x * 64 + lane]; vv[ii] = dis[p[ii].x]; }
#pragma unroll
        for (int ii = 0; ii < 8; ++ii) {
            float v = __int_as_float(p[ii].y) * vv[ii];
            ax += bf16_lo(h[ii]) * v;
            ay += bf16_hi(h[ii]) * v;
        }
    }
    for (; j < end; ++j) {
        int2 p0 = pairs[j];
        unsigned int h0 = Hb[(size_t)p0.x * 64 + lane];
        float v0 = __int_as_float(p0.y) * dis[p0.x];
        ax += bf16_lo(h0) * v0;
        ay += bf16_hi(h0) * v0;
    }

    float dd = dis[node];
    float sn = dd * dd;
    unsigned int hs = Hb[(size_t)node * 64 + lane];
    float2 bb = ((const float2*)b)[lane];
    float ox = ax * dd + bf16_lo(hs) * sn + bb.x;
    float oy = ay * dd + bf16_hi(hs) * sn + bb.y;
    ((float2*)(out + (size_t)i * D))[lane] = make_float2(ox, oy);
    if (lane == 0) out[(size_t)M * D + i] = (float)y[node];
}

extern "C" void kernel_launch(void* const* d_in, const int* in_sizes, int n_in,
                              void* d_out, int out_size, void* d_ws, size_t ws_size,
                              hipStream_t stream) {
    const float* x  = (const float*)d_in[0];
    const float* ew = (const float*)d_in[1];
    const float* W1 = (const float*)d_in[2];
    const float* b1 = (const float*)d_in[3];
    const float* W2 = (const float*)d_in[4];
    const float* b2 = (const float*)d_in[5];
    const int* eidx = (const int*)d_in[6];
    const int* mask = (const int*)d_in[7];
    const int* y    = (const int*)d_in[8];
    const int* src = eidx;       // edge_index[0]
    const int* dst = eidx + E;   // edge_index[1]

    // Workspace layout (bytes):
    //   dis       @ 0        : N f32          (0.4 MB)
    //   rowBE     @ 512 KB   : N int2         (0.8 MB)
    //   maskbit   @ 1344 KB  : 16 KB bitmap }
    //   needed    @ 1360 KB  : 16 KB bitmap }  one 33 KB memset covers all three
    //   cursors   @ 1376 KB  : NB i32       }
    //   Wt1       @ 1408 KB  : 8192 u32       (32 KB)
    //   Wt2       @ 1440 KB  : 8192 u32       (32 KB)
    //   tmp       @ 2 MB     : NB*CAP u64     (16.1 MB)
    //   pairs     @ 19 MB    : NB*CAP int2    (16.1 MB)
    //   A  (bf16) @ 36 MB    : N*D bf16       (25.6 MB)
    //   B  (bf16) @ 62 MB    : N*D bf16       (25.6 MB)
    //   A2 (bf16) @ 88 MB    : N*D bf16       (25.6 MB)   total ~113.6 MB
    char* ws = (char*)d_ws;
    float* dis      = (float*)(ws);
    int2*  rowBE    = (int2*)(ws + (size_t)512 * 1024);
    unsigned int* maskbit = (unsigned int*)(ws + (size_t)1344 * 1024);
    unsigned int* needed  = (unsigned int*)(ws + (size_t)1360 * 1024);
    int*   cursors  = (int*)(ws + (size_t)1376 * 1024);
    unsigned int* Wt1 = (unsigned int*)(ws + (size_t)1408 * 1024);
    unsigned int* Wt2 = (unsigned int*)(ws + (size_t)1440 * 1024);
    unsigned long long* tmp = (unsigned long long*)(ws + (size_t)2 * 1024 * 1024);
    int2*  pairs    = (int2*)(ws + (size_t)19 * 1024 * 1024);
    unsigned short* A  = (unsigned short*)(ws + (size_t)36 * 1024 * 1024);
    unsigned short* B  = (unsigned short*)(ws + (size_t)62 * 1024 * 1024);
    unsigned short* A2 = (unsigned short*)(ws + (size_t)88 * 1024 * 1024);

    // --- zero bitmaps + cursors (contiguous 33 KB), then prep + maskbit ---
    (void)hipMemsetAsync(maskbit, 0, (size_t)33 * 1024, stream);
    hipLaunchKernelGGL(k_misc1, dim3(PREP_BLKS + MB_BLKS), dim3(256), 0, stream,
                       W1, Wt1, W2, Wt2, mask, maskbit, needed);

    // --- bucketed CSR build: partition (reserve+scatter, fused needed-scan) + local sort ---
    hipLaunchKernelGGL(k_part, dim3(NPB), dim3(256), 0, stream,
                       src, dst, ew, maskbit, needed, cursors, tmp);
    hipLaunchKernelGGL(k_local, dim3(NB), dim3(256), 0, stream,
                       tmp, cursors, dis, rowBE, pairs);

    // --- layer 1: A = x@W1 (MFMA) ; B = relu(agg(A) + b1) at needed nodes only ---
    hipLaunchKernelGGL(k_gemm1, dim3(MF_BLKS), dim3(256), 0, stream, x, Wt1, A);
    hipLaunchKernelGGL(k_aggregate, dim3((N + 3) / 4), dim3(256), 0, stream,
                       (const unsigned int*)A, pairs, rowBE, dis, needed, b1,
                       (unsigned int*)B);

    // --- layer 2: A2 = B@W2 (MFMA) ; out = agg(A2) at mask nodes ---
    hipLaunchKernelGGL(k_gemm2, dim3(MF_BLKS), dim3(256), 0, stream, B, Wt2, A2);
    hipLaunchKernelGGL(k_aggregate_mask, dim3((M + 3) / 4), dim3(256), 0, stream,
                       (const unsigned int*)A2, pairs, rowBE, dis, b2, mask, y, (float*)d_out);
}